// Round 4
// baseline (464.425 us; speedup 1.0000x reference)
//
#include <hip/hip_runtime.h>

#define FDIM 128
typedef float v2f __attribute__((ext_vector_type(2)));

// ---------------------------------------------------------------------------
// CSR build step 1: histogram of row counts (int4 reads, 4 atomics/thread)
// ---------------------------------------------------------------------------
__global__ __launch_bounds__(256) void hist_rows(
    const int* __restrict__ row, int* __restrict__ counts, int nedges)
{
    int t = blockIdx.x * 256 + threadIdx.x;
    int base = t * 4;
    if (base + 4 <= nedges) {
        int4 r = *reinterpret_cast<const int4*>(row + base);
        atomicAdd(&counts[r.x], 1);
        atomicAdd(&counts[r.y], 1);
        atomicAdd(&counts[r.z], 1);
        atomicAdd(&counts[r.w], 1);
    } else {
        for (int e = base; e < nedges; ++e)
            atomicAdd(&counts[row[e]], 1);
    }
}

// ---------------------------------------------------------------------------
// CSR build step 2a: per-block exclusive scan (1024 elems/block of 256 thr)
// ---------------------------------------------------------------------------
__global__ __launch_bounds__(256) void scan_block(
    const int* __restrict__ in, int* __restrict__ out,
    int* __restrict__ partials, int n)
{
    __shared__ int s[256];
    const int tid  = threadIdx.x;
    const int base = blockIdx.x * 1024 + tid * 4;

    int v[4];
    int t = 0;
    #pragma unroll
    for (int k = 0; k < 4; ++k) {
        v[k] = (base + k < n) ? in[base + k] : 0;
        t += v[k];
    }
    s[tid] = t;
    __syncthreads();
    #pragma unroll
    for (int off = 1; off < 256; off <<= 1) {
        int add = (tid >= off) ? s[tid - off] : 0;
        __syncthreads();
        s[tid] += add;
        __syncthreads();
    }
    int run = s[tid] - t;
    #pragma unroll
    for (int k = 0; k < 4; ++k) {
        if (base + k < n) out[base + k] = run;
        run += v[k];
    }
    if (tid == 255) partials[blockIdx.x] = s[255];
}

// ---------------------------------------------------------------------------
// CSR build step 2b: exclusive scan of block totals (single block)
// ---------------------------------------------------------------------------
__global__ __launch_bounds__(1024) void scan_partials(
    int* __restrict__ partials, int n)
{
    __shared__ int s[1024];
    const int tid = threadIdx.x;
    int t = (tid < n) ? partials[tid] : 0;
    s[tid] = t;
    __syncthreads();
    #pragma unroll
    for (int off = 1; off < 1024; off <<= 1) {
        int add = (tid >= off) ? s[tid - off] : 0;
        __syncthreads();
        s[tid] += add;
        __syncthreads();
    }
    if (tid < n) partials[tid] = s[tid] - t;
}

// ---------------------------------------------------------------------------
// CSR build step 2c: add scanned block offsets
// ---------------------------------------------------------------------------
__global__ __launch_bounds__(256) void scan_add(
    int* __restrict__ out, const int* __restrict__ partials, int n)
{
    const int add  = partials[blockIdx.x];
    const int base = blockIdx.x * 1024 + threadIdx.x * 4;
    #pragma unroll
    for (int k = 0; k < 4; ++k)
        if (base + k < n) out[base + k] += add;
}

// ---------------------------------------------------------------------------
// CSR build step 3: bucket fill with PACKED (col,val) 8B scatter.
// Destructively advances rowptr[r]; after this kernel rowptr[r] == end ptr.
// ---------------------------------------------------------------------------
__global__ __launch_bounds__(256) void csr_fill(
    const int* __restrict__ row, const int* __restrict__ col,
    const float* __restrict__ val, int* __restrict__ rowptr,
    unsigned long long* __restrict__ epack, int nedges)
{
    int e = blockIdx.x * 256 + threadIdx.x;
    if (e < nedges) {
        int r = row[e];
        int slot = atomicAdd(&rowptr[r], 1);
        unsigned long long pk =
            ((unsigned long long)__float_as_uint(val[e]) << 32) |
            (unsigned int)col[e];
        epack[slot] = pk;
    }
}

// ---------------------------------------------------------------------------
// SpMM (CSR gather): out[r] = sum_e val[e] * y[col[e]]  — one wave per row,
// lane owns 2 features, 4-edge unroll for MLP, nontemporal final store.
// ---------------------------------------------------------------------------
__global__ __launch_bounds__(256) void spmm_csr(
    const int* __restrict__ rowptr,
    const unsigned long long* __restrict__ epack,
    const float* __restrict__ y, float* __restrict__ out, int M)
{
    const int row = blockIdx.x * 4 + (threadIdx.x >> 6);
    if (row >= M) return;
    const int lane = threadIdx.x & 63;

    const int start = (row == 0) ? 0 : rowptr[row - 1];
    const int end   = rowptr[row];

    float ax = 0.f, ay = 0.f;
    int j = start;
    for (; j + 4 <= end; j += 4) {
        unsigned long long p0 = epack[j + 0];
        unsigned long long p1 = epack[j + 1];
        unsigned long long p2 = epack[j + 2];
        unsigned long long p3 = epack[j + 3];
        v2f x0 = *reinterpret_cast<const v2f*>(
            y + (size_t)(unsigned)(p0 & 0xffffffffu) * FDIM + lane * 2);
        v2f x1 = *reinterpret_cast<const v2f*>(
            y + (size_t)(unsigned)(p1 & 0xffffffffu) * FDIM + lane * 2);
        v2f x2 = *reinterpret_cast<const v2f*>(
            y + (size_t)(unsigned)(p2 & 0xffffffffu) * FDIM + lane * 2);
        v2f x3 = *reinterpret_cast<const v2f*>(
            y + (size_t)(unsigned)(p3 & 0xffffffffu) * FDIM + lane * 2);
        float v0 = __uint_as_float((unsigned)(p0 >> 32));
        float v1 = __uint_as_float((unsigned)(p1 >> 32));
        float v2 = __uint_as_float((unsigned)(p2 >> 32));
        float v3 = __uint_as_float((unsigned)(p3 >> 32));
        ax = fmaf(v0, x0.x, ax); ay = fmaf(v0, x0.y, ay);
        ax = fmaf(v1, x1.x, ax); ay = fmaf(v1, x1.y, ay);
        ax = fmaf(v2, x2.x, ax); ay = fmaf(v2, x2.y, ay);
        ax = fmaf(v3, x3.x, ax); ay = fmaf(v3, x3.y, ay);
    }
    for (; j < end; ++j) {
        unsigned long long p0 = epack[j];
        v2f x0 = *reinterpret_cast<const v2f*>(
            y + (size_t)(unsigned)(p0 & 0xffffffffu) * FDIM + lane * 2);
        float v0 = __uint_as_float((unsigned)(p0 >> 32));
        ax = fmaf(v0, x0.x, ax); ay = fmaf(v0, x0.y, ay);
    }
    v2f acc = {ax, ay};
    __builtin_nontemporal_store(
        acc, reinterpret_cast<v2f*>(out + (size_t)row * FDIM + lane * 2));
}

// ---------------------------------------------------------------------------
// GEMM: y[M,128] = x[M,128] @ W[128,128]   (fp32 vector ALU)
// ---------------------------------------------------------------------------
__global__ __launch_bounds__(256, 2) void gemm_xw(
    const float* __restrict__ x, const float* __restrict__ w,
    float* __restrict__ y, int M)
{
    __shared__ float sZt[128 * 65];
    __shared__ float sW[64 * 132];

    const int tidx = threadIdx.x;
    const int rowBase = blockIdx.x * 64;

    #pragma unroll
    for (int i = 0; i < 8; ++i) {
        int idx = tidx + 256 * i;
        int r   = idx >> 5;
        int k4  = idx & 31;
        float4 v = make_float4(0.f, 0.f, 0.f, 0.f);
        if (rowBase + r < M)
            v = *reinterpret_cast<const float4*>(
                x + (size_t)(rowBase + r) * FDIM + k4 * 4);
        sZt[(k4 * 4 + 0) * 65 + r] = v.x;
        sZt[(k4 * 4 + 1) * 65 + r] = v.y;
        sZt[(k4 * 4 + 2) * 65 + r] = v.z;
        sZt[(k4 * 4 + 3) * 65 + r] = v.w;
    }

    const int ty = tidx >> 4;
    const int tx = tidx & 15;
    const int r0 = ty * 4;
    const int c0 = tx * 4;

    float acc[4][8] = {};

    for (int kc = 0; kc < 128; kc += 64) {
        __syncthreads();
        #pragma unroll
        for (int i = 0; i < 8; ++i) {
            int idx = tidx + 256 * i;
            int k   = idx >> 5;
            int c4  = idx & 31;
            float4 v = *reinterpret_cast<const float4*>(
                w + (size_t)(kc + k) * FDIM + c4 * 4);
            *reinterpret_cast<float4*>(&sW[k * 132 + c4 * 4]) = v;
        }
        __syncthreads();

        #pragma unroll 8
        for (int kk = 0; kk < 64; ++kk) {
            int k = kc + kk;
            float4 zv = *reinterpret_cast<const float4*>(&sZt[k * 65 + r0]);
            float4 w0 = *reinterpret_cast<const float4*>(&sW[kk * 132 + c0]);
            float4 w1 = *reinterpret_cast<const float4*>(&sW[kk * 132 + c0 + 64]);
            float zr[4] = {zv.x, zv.y, zv.z, zv.w};
            float wv[8] = {w0.x, w0.y, w0.z, w0.w, w1.x, w1.y, w1.z, w1.w};
            #pragma unroll
            for (int i = 0; i < 4; ++i)
                #pragma unroll
                for (int j = 0; j < 8; ++j)
                    acc[i][j] += zr[i] * wv[j];
        }
    }

    #pragma unroll
    for (int i = 0; i < 4; ++i) {
        int r = rowBase + r0 + i;
        if (r < M) {
            float4 o0 = make_float4(acc[i][0], acc[i][1], acc[i][2], acc[i][3]);
            float4 o1 = make_float4(acc[i][4], acc[i][5], acc[i][6], acc[i][7]);
            *reinterpret_cast<float4*>(y + (size_t)r * FDIM + c0)      = o0;
            *reinterpret_cast<float4*>(y + (size_t)r * FDIM + c0 + 64) = o1;
        }
    }
}

extern "C" void kernel_launch(void* const* d_in, const int* in_sizes, int n_in,
                              void* d_out, int out_size, void* d_ws, size_t ws_size,
                              hipStream_t stream) {
    const int*   row = (const int*)d_in[0];
    const int*   col = (const int*)d_in[1];
    const float* val = (const float*)d_in[2];
    const float* x   = (const float*)d_in[3];
    const float* w   = (const float*)d_in[4];
    float* out = (float*)d_out;

    const int E = in_sizes[0];
    const int M = in_sizes[3] / FDIM;   // 100000

    char* ws = (char*)d_ws;
    size_t off = 0;
    auto carve = [&](size_t bytes) {
        void* p = ws + off;
        off += (bytes + 255) & ~(size_t)255;
        return p;
    };
    float*              y        = (float*)carve((size_t)M * FDIM * sizeof(float));
    int*                rowptr   = (int*)  carve((size_t)M * sizeof(int));
    int*                counts   = (int*)  carve((size_t)M * sizeof(int));
    unsigned long long* epack    = (unsigned long long*)carve((size_t)E * 8);
    int*                partials = (int*)  carve(1024 * sizeof(int));

    const int NBLK = (M + 1023) / 1024;   // 98 (<=1024 required)

    // y = x @ W  (independent of CSR build)
    gemm_xw<<<(M + 63) / 64, 256, 0, stream>>>(x, w, y, M);

    hipMemsetAsync(counts, 0, (size_t)M * sizeof(int), stream);
    hist_rows<<<(E / 4 + 255) / 256, 256, 0, stream>>>(row, counts, E);
    scan_block<<<NBLK, 256, 0, stream>>>(counts, rowptr, partials, M);
    scan_partials<<<1, 1024, 0, stream>>>(partials, NBLK);
    scan_add<<<NBLK, 256, 0, stream>>>(rowptr, partials, M);
    csr_fill<<<(E + 255) / 256, 256, 0, stream>>>(row, col, val, rowptr,
                                                  epack, E);
    // out = A @ y
    spmm_csr<<<(M + 3) / 4, 256, 0, stream>>>(rowptr, epack, y, out, M);
}